// Round 7
// baseline (97.606 us; speedup 1.0000x reference)
//
#include <hip/hip_runtime.h>

#define NROWS 8192
#define NCOLS 4096
#define LAMB  0.1

typedef unsigned long long u64;

// ---------------------------------------------------------------------------
// Kernel 1: per-row squared error sum. One wave per 2 rows, 1024 blocks x 256.
// In-bench this runs at the read roofline (~41 us for 268 MB).
// Also zeroes the ticket counter for kernel 2 (kernel-boundary fence orders it).
// ---------------------------------------------------------------------------
__global__ __launch_bounds__(256, 4) void rowerr_kernel(const float* __restrict__ inp,
                                                        const float* __restrict__ tgt,
                                                        float* __restrict__ err,
                                                        int* __restrict__ counter) {
    if (blockIdx.x == 0 && threadIdx.x == 0) counter[0] = 0;

    const int lane = threadIdx.x & 63;
    const int wid  = blockIdx.x * 4 + (threadIdx.x >> 6);   // 0..4095

#pragma unroll
    for (int rr = 0; rr < 2; ++rr) {
        const int row = wid * 2 + rr;
        const float4* a = reinterpret_cast<const float4*>(inp + (size_t)row * NCOLS);
        const float4* b = reinterpret_cast<const float4*>(tgt + (size_t)row * NCOLS);

        float acc0 = 0.f, acc1 = 0.f, acc2 = 0.f, acc3 = 0.f;
#pragma unroll
        for (int c = 0; c < 16; ++c) {
            const float4 va = a[lane + c * 64];
            const float4 vb = b[lane + c * 64];
            const float dx = va.x - vb.x;
            const float dy = va.y - vb.y;
            const float dz = va.z - vb.z;
            const float dw = va.w - vb.w;
            acc0 += dx * dx;
            acc1 += dy * dy;
            acc2 += dz * dz;
            acc3 += dw * dw;
        }
        float acc = (acc0 + acc1) + (acc2 + acc3);

#pragma unroll
        for (int off = 32; off > 0; off >>= 1) acc += __shfl_down(acc, off, 64);

        if (lane == 0) err[row] = acc;
    }
}

// ---------------------------------------------------------------------------
// fast f64 reciprocal: f32 seed + 2 Newton steps (~1 ulp, no f64 divide)
// ---------------------------------------------------------------------------
__device__ __forceinline__ double fastrcp(double x) {
    double r = (double)(1.0f / (float)x);
    r = r * (2.0 - x * r);
    r = r * (2.0 - x * r);
    return r;
}

// ---------------------------------------------------------------------------
// Kernel 2: rank-and-scatter sort over 128 CUs + fused obj phase (last block).
// Sortable key = (float_bits << 32) | index  (all errs >= 0, so float bit
// pattern is order-monotone; index makes keys unique -> exact stable perm).
// Block b owns elems i = b*64 + lane; wave wv counts over j-slice [wv*512,+512)
// via broadcast LDS reads. Wave 0 sums 16 partials -> rank -> scatter.
// Last block (device-scope ticket) then runs the scan+argmax epilogue:
//   argmin (Sw1+Sw2)/Sb == argmax h(k) = cs_k^2/k + (total-cs_k)^2/(n-k).
// ---------------------------------------------------------------------------
__global__ __launch_bounds__(1024) void rank_obj_kernel(const float* __restrict__ err,
                                                        float* __restrict__ sorted,
                                                        int* __restrict__ counter,
                                                        float* __restrict__ out) {
    const int N = NROWS;
    __shared__ u64 keys[NROWS];       // 64 KB
    __shared__ int part[16 * 64];
    __shared__ int ticketSh;
    __shared__ double auxX[16], auxT2[16], redH[16], redCs[16];
    __shared__ int    redIdx[16];

    const int tid = threadIdx.x;
    const int lane = tid & 63, wv = tid >> 6;

    // ---- stage sortable keys into LDS (coalesced global, 2-way-free LDS) ----
#pragma unroll
    for (int k = 0; k < 8; ++k) {
        const int i = tid + k * 1024;
        keys[i] = ((u64)__float_as_uint(err[i]) << 32) | (unsigned)i;
    }
    __syncthreads();

    // ---- count: rank of my element within wave's j-slice ----
    const int myi = blockIdx.x * 64 + lane;
    const u64 ki  = keys[myi];

    unsigned cnt = 0;
    const int j0 = wv * 512;
#pragma unroll 8
    for (int j = 0; j < 512; ++j) {
        cnt += (keys[j0 + j] < ki) ? 1u : 0u;   // broadcast LDS read
    }
    part[wv * 64 + lane] = cnt;
    __syncthreads();

    // ---- combine partials, scatter to sorted[rank] ----
    if (wv == 0) {
        int rank = 0;
#pragma unroll
        for (int w = 0; w < 16; ++w) rank += part[w * 64 + lane];
        sorted[rank] = __uint_as_float((unsigned)(ki >> 32));
    }

    // ---- device-scope release + ticket ----
    __threadfence();
    __syncthreads();
    if (tid == 0) ticketSh = atomicAdd(counter, 1);
    __syncthreads();
    if (ticketSh != (int)gridDim.x - 1) return;

    __threadfence();   // acquire: don't read stale sorted[] lines

    // ================= obj phase (last block only, 1024 threads) ============
    float v[8];
    {
        const float4* s4 = reinterpret_cast<const float4*>(sorted);
        float4 a = s4[tid * 2];
        float4 b = s4[tid * 2 + 1];
        v[0] = a.x; v[1] = a.y; v[2] = a.z; v[3] = a.w;
        v[4] = b.x; v[5] = b.y; v[6] = b.z; v[7] = b.w;
    }

    double sx = 0.0, sx2 = 0.0;
#pragma unroll
    for (int r = 0; r < 8; ++r) {
        sx  += (double)v[r];
        sx2 += (double)v[r] * (double)v[r];
    }

    // wave inclusive scan of sx; wave total of sx2
    double ix = sx;
#pragma unroll
    for (int off = 1; off < 64; off <<= 1) {
        double t1 = __shfl_up(ix, off, 64);
        if (lane >= off) ix += t1;
    }
    double t2 = sx2;
#pragma unroll
    for (int off = 32; off > 0; off >>= 1) t2 += __shfl_xor(t2, off, 64);

    if (lane == 63) auxX[wv]  = ix;
    if (lane == 0)  auxT2[wv] = t2;
    __syncthreads();

    double wOff1 = 0.0, total1 = 0.0, total2 = 0.0;
#pragma unroll
    for (int w = 0; w < 16; ++w) {
        const double a1 = auxX[w];
        if (w < wv) wOff1 += a1;
        total1 += a1;
        total2 += auxT2[w];
    }
    const double exc1 = wOff1 + (ix - sx);   // exclusive prefix before this chunk
    const double nf = (double)N;

    // on-the-fly h(k) evaluation + local argmax (== argmin obj), first idx tie
    double run1 = exc1;
    double bestH = -1e300, bestCs = 0.0;
    int bestIdx = N;
#pragma unroll
    for (int r = 0; r < 8; ++r) {
        const int idx = (tid << 3) + r;
        run1 += (double)v[r];
        if (idx < N - 1) {
            const double kf  = (double)(idx + 1);
            const double rem = total1 - run1;
            const double h   = run1 * run1 * fastrcp(kf) +
                               rem  * rem  * fastrcp(nf - kf);
            if (h > bestH) { bestH = h; bestIdx = idx; bestCs = run1; }
        }
    }

    // wave argmax reduce (max h, first index on ties)
#pragma unroll
    for (int off = 32; off > 0; off >>= 1) {
        const double oH   = __shfl_down(bestH, off, 64);
        const int    oIdx = __shfl_down(bestIdx, off, 64);
        const double oCs  = __shfl_down(bestCs, off, 64);
        if (oH > bestH || (oH == bestH && oIdx < bestIdx)) {
            bestH = oH; bestIdx = oIdx; bestCs = oCs;
        }
    }
    if (lane == 0) { redH[wv] = bestH; redIdx[wv] = bestIdx; redCs[wv] = bestCs; }
    __syncthreads();

    if (tid == 0) {
        double bH = redH[0], bCs = redCs[0];
        int bIdx = redIdx[0];
        for (int w = 1; w < 16; ++w) {
            if (redH[w] > bH || (redH[w] == bH && redIdx[w] < bIdx)) {
                bH = redH[w]; bIdx = redIdx[w]; bCs = redCs[w];
            }
        }
        const double Sb     = total2 - total1 * total1 / nf;
        const double optObj = (total2 - bH) / Sb;
        const double T      = (double)(bIdx + 1);
        out[0] = (float)(bCs / T + LAMB * optObj);
    }
}

// ---------------------------------------------------------------------------
extern "C" void kernel_launch(void* const* d_in, const int* in_sizes, int n_in,
                              void* d_out, int out_size, void* d_ws, size_t ws_size,
                              hipStream_t stream) {
    const float* inp = (const float*)d_in[0];
    const float* tgt = (const float*)d_in[1];
    float* errbuf    = (float*)d_ws;              // 8192 f32
    float* sortedbuf = (float*)d_ws + NROWS;      // 8192 f32
    int*   counter   = (int*)((float*)d_ws + 2 * NROWS);

    rowerr_kernel<<<NROWS / 8, 256, 0, stream>>>(inp, tgt, errbuf, counter);
    rank_obj_kernel<<<NROWS / 64, 1024, 0, stream>>>(errbuf, sortedbuf, counter,
                                                     (float*)d_out);
}

// Round 8
// 73.958 us; speedup vs baseline: 1.3198x; 1.3198x over previous
//
#include <hip/hip_runtime.h>

#define NROWS 8192
#define NCOLS 4096
#define LAMB  0.1

typedef unsigned int u32;
typedef unsigned long long u64;

// ---------------------------------------------------------------------------
// Kernel 1: per-row squared error sum. One wave per 2 rows, 1024 blocks x 256.
// In steady-state (graph replay, warm L3) this runs at the read roofline.
// ---------------------------------------------------------------------------
__global__ __launch_bounds__(256, 4) void rowerr_kernel(const float* __restrict__ inp,
                                                        const float* __restrict__ tgt,
                                                        float* __restrict__ err) {
    const int lane = threadIdx.x & 63;
    const int wid  = blockIdx.x * 4 + (threadIdx.x >> 6);   // 0..4095

#pragma unroll
    for (int rr = 0; rr < 2; ++rr) {
        const int row = wid * 2 + rr;
        const float4* a = reinterpret_cast<const float4*>(inp + (size_t)row * NCOLS);
        const float4* b = reinterpret_cast<const float4*>(tgt + (size_t)row * NCOLS);

        float acc0 = 0.f, acc1 = 0.f, acc2 = 0.f, acc3 = 0.f;
#pragma unroll
        for (int c = 0; c < 16; ++c) {
            const float4 va = a[lane + c * 64];
            const float4 vb = b[lane + c * 64];
            const float dx = va.x - vb.x;
            const float dy = va.y - vb.y;
            const float dz = va.z - vb.z;
            const float dw = va.w - vb.w;
            acc0 += dx * dx;
            acc1 += dy * dy;
            acc2 += dz * dz;
            acc3 += dw * dw;
        }
        float acc = (acc0 + acc1) + (acc2 + acc3);

#pragma unroll
        for (int off = 32; off > 0; off >>= 1) acc += __shfl_down(acc, off, 64);

        if (lane == 0) err[row] = acc;
    }
}

// ---------------------------------------------------------------------------
// fast f64 reciprocal: f32 seed + 2 Newton steps (~1 ulp, no f64 divide)
// ---------------------------------------------------------------------------
__device__ __forceinline__ double fastrcp(double x) {
    double r = (double)(1.0f / (float)x);
    r = r * (2.0 - x * r);
    r = r * (2.0 - x * r);
    return r;
}

// ---------------------------------------------------------------------------
// Kernel 2: single block, 1024 threads (16 waves), LSD RADIX-256 sort in LDS
// (4 passes over 8192 u32 keys = float bits, all non-negative -> monotone).
// Per pass:
//   - ballot-based multi-split: 8 ballots identify same-digit lanes; rank
//     within (wave,digit) kept in an LDS running histogram (lockstep-safe
//     read-then-leader-write, no atomics).
//   - element->lane map is STRIDED (w*512 + r*64 + lane) so slot-major
//     processing order == array order -> stable LSD radix.
//   - digit-column scan over the 16 wave histograms + 256-wide exclusive
//     scan gives the global scatter base.
// Then the fused obj phase: f64 scan of cs, block-total of cs2, argmax of
//   h(k) = cs_k^2/k + (total-cs_k)^2/(n-k)   (== argmin (Sw1+Sw2)/Sb).
// Equal values are interchangeable -> key-only sort is exact for this use.
// ---------------------------------------------------------------------------
__global__ __launch_bounds__(1024) void drae_kernel(const float* __restrict__ err,
                                                    float* __restrict__ out) {
    const int N = NROWS;
    __shared__ u32 bufA[NROWS];          // 32 KB
    __shared__ u32 bufB[NROWS];          // 32 KB
    __shared__ u32 hist[16 * 256];       // 16 KB
    __shared__ u32 dtot[256], dbase[256];
    __shared__ u32 saux[4];
    __shared__ double auxX[16], auxT2[16], redH[16], redCs[16];
    __shared__ int    redIdx[16];

    const int tid  = threadIdx.x;
    const int lane = tid & 63, wv = tid >> 6;
    const u64 ltmask = (1ull << lane) - 1ull;

    // ---- stage float bits into LDS (coalesced) ----
#pragma unroll
    for (int k = 0; k < 8; ++k) {
        const int i = tid + k * 1024;
        bufA[i] = __float_as_uint(err[i]);
    }

    u32* src = bufA;
    u32* dst = bufB;

    for (int pass = 0; pass < 4; ++pass) {
        const int shift = pass * 8;

        __syncthreads();                       // prev scatter / staging visible
#pragma unroll
        for (int k = 0; k < 4; ++k) hist[tid + k * 1024] = 0;
        __syncthreads();                       // hist zeroed

        // ---- read keys (strided: array idx = wv*512 + r*64 + lane) ----
        u32 key[8], rnk[8];
#pragma unroll
        for (int r = 0; r < 8; ++r) key[r] = src[wv * 512 + r * 64 + lane];

        // ---- ballot multi-split: rank within (wave, digit), array order ----
#pragma unroll
        for (int r = 0; r < 8; ++r) {
            const u32 d = (key[r] >> shift) & 255u;
            u64 match = ~0ull;
#pragma unroll
            for (int b = 0; b < 8; ++b) {
                const u64 bb = __ballot((d >> b) & 1u);
                match &= ((d >> b) & 1u) ? bb : ~bb;
            }
            const int within = __popcll(match & ltmask);
            const int leader = __builtin_ctzll(match);      // match != 0 (self)
            const u32 base = hist[wv * 256 + d];            // group broadcast
            rnk[r] = base + (u32)within;
            if (lane == leader) hist[wv * 256 + d] = base + (u32)__popcll(match);
        }
        __syncthreads();                       // all wave histograms complete

        // ---- per-digit column scan over waves; dtot[d] = digit total ----
        if (tid < 256) {
            u32 s = 0;
#pragma unroll
            for (int w = 0; w < 16; ++w) {
                const u32 t = hist[w * 256 + tid];
                hist[w * 256 + tid] = s;       // exclusive over waves
                s += t;
            }
            dtot[tid] = s;
        }
        __syncthreads();

        // ---- exclusive scan of dtot[256] -> dbase ----
        u32 val = 0, incl = 0;
        if (tid < 256) {
            val  = dtot[tid];
            incl = val;
#pragma unroll
            for (int off = 1; off < 64; off <<= 1) {
                const u32 t = __shfl_up(incl, off, 64);
                if (lane >= off) incl += t;
            }
            if (lane == 63) saux[wv] = incl;   // wv in 0..3 here
        }
        __syncthreads();
        if (tid < 256) {
            u32 add = 0;
#pragma unroll
            for (int w = 0; w < 4; ++w) if (w < wv) add += saux[w];
            dbase[tid] = incl - val + add;
        }
        __syncthreads();

        // ---- stable scatter ----
#pragma unroll
        for (int r = 0; r < 8; ++r) {
            const u32 d = (key[r] >> shift) & 255u;
            dst[dbase[d] + hist[wv * 256 + d] + rnk[r]] = key[r];
        }

        u32* tmp = src; src = dst; dst = tmp;  // A->B->A->B->A
    }
    __syncthreads();                           // src (==bufA) fully sorted

    // ================= obj phase (same block) ==============================
    float v[8];
#pragma unroll
    for (int r = 0; r < 8; ++r) v[r] = __uint_as_float(src[(tid << 3) + r]);

    double sx = 0.0, sx2 = 0.0;
#pragma unroll
    for (int r = 0; r < 8; ++r) {
        sx  += (double)v[r];
        sx2 += (double)v[r] * (double)v[r];
    }

    // wave inclusive scan of sx; wave total of sx2
    double ix = sx;
#pragma unroll
    for (int off = 1; off < 64; off <<= 1) {
        double t1 = __shfl_up(ix, off, 64);
        if (lane >= off) ix += t1;
    }
    double t2 = sx2;
#pragma unroll
    for (int off = 32; off > 0; off >>= 1) t2 += __shfl_xor(t2, off, 64);

    if (lane == 63) auxX[wv]  = ix;
    if (lane == 0)  auxT2[wv] = t2;
    __syncthreads();

    double wOff1 = 0.0, total1 = 0.0, total2 = 0.0;
#pragma unroll
    for (int w = 0; w < 16; ++w) {
        const double a1 = auxX[w];
        if (w < wv) wOff1 += a1;
        total1 += a1;
        total2 += auxT2[w];
    }
    const double exc1 = wOff1 + (ix - sx);   // exclusive prefix before this chunk
    const double nf = (double)N;

    // on-the-fly h(k) + local argmax (== argmin obj), first index on ties
    double run1 = exc1;
    double bestH = -1e300, bestCs = 0.0;
    int bestIdx = N;
#pragma unroll
    for (int r = 0; r < 8; ++r) {
        const int idx = (tid << 3) + r;
        run1 += (double)v[r];
        if (idx < N - 1) {
            const double kf  = (double)(idx + 1);
            const double rem = total1 - run1;
            const double h   = run1 * run1 * fastrcp(kf) +
                               rem  * rem  * fastrcp(nf - kf);
            if (h > bestH) { bestH = h; bestIdx = idx; bestCs = run1; }
        }
    }

    // wave argmax reduce (max h, first index on ties)
#pragma unroll
    for (int off = 32; off > 0; off >>= 1) {
        const double oH   = __shfl_down(bestH, off, 64);
        const int    oIdx = __shfl_down(bestIdx, off, 64);
        const double oCs  = __shfl_down(bestCs, off, 64);
        if (oH > bestH || (oH == bestH && oIdx < bestIdx)) {
            bestH = oH; bestIdx = oIdx; bestCs = oCs;
        }
    }
    if (lane == 0) { redH[wv] = bestH; redIdx[wv] = bestIdx; redCs[wv] = bestCs; }
    __syncthreads();

    if (tid == 0) {
        double bH = redH[0], bCs = redCs[0];
        int bIdx = redIdx[0];
        for (int w = 1; w < 16; ++w) {
            if (redH[w] > bH || (redH[w] == bH && redIdx[w] < bIdx)) {
                bH = redH[w]; bIdx = redIdx[w]; bCs = redCs[w];
            }
        }
        const double Sb     = total2 - total1 * total1 / nf;
        const double optObj = (total2 - bH) / Sb;
        const double T      = (double)(bIdx + 1);
        out[0] = (float)(bCs / T + LAMB * optObj);
    }
}

// ---------------------------------------------------------------------------
extern "C" void kernel_launch(void* const* d_in, const int* in_sizes, int n_in,
                              void* d_out, int out_size, void* d_ws, size_t ws_size,
                              hipStream_t stream) {
    const float* inp = (const float*)d_in[0];
    const float* tgt = (const float*)d_in[1];
    float* errbuf = (float*)d_ws;   // 8192 f32 = 32 KB scratch

    rowerr_kernel<<<NROWS / 8, 256, 0, stream>>>(inp, tgt, errbuf);
    drae_kernel<<<1, 1024, 0, stream>>>(errbuf, (float*)d_out);
}